// Round 3
// baseline (228.109 us; speedup 1.0000x reference)
//
#include <hip/hip_runtime.h>
#include <stdint.h>

#define NB 4096
#define TT 64
#define CC 128
#define HH 64

#define WSTR 136   // weight/P LDS row stride (bf16 elems): 128 + 8 pad
#define QSTR 72    // q/k/vT LDS row stride: 64 + 8 pad

typedef __bf16 bf16x8 __attribute__((ext_vector_type(8)));
typedef float f32x4 __attribute__((ext_vector_type(4)));

__device__ __forceinline__ unsigned short f2bf(float f) {
  union { float f; uint32_t u; } a; a.f = f;
  uint32_t u = a.u;
  u += 0x7fffu + ((u >> 16) & 1u);   // round-to-nearest-even
  return (unsigned short)(u >> 16);
}

// Transpose the three [C,H] fp32 weight matrices into bf16 wT[mat][h][c].
__global__ void transpose_w_kernel(const float* __restrict__ Wq,
                                   const float* __restrict__ Wk,
                                   const float* __restrict__ Wv,
                                   unsigned short* __restrict__ wT) {
  int i = blockIdx.x * 256 + threadIdx.x;
  if (i >= 3 * CC * HH) return;
  int mat = i / (CC * HH);
  int r   = i % (CC * HH);
  int c   = r / HH;
  int h   = r % HH;
  const float* W = (mat == 0) ? Wq : (mat == 1) ? Wk : Wv;
  wT[mat * (CC * HH) + h * CC + c] = f2bf(W[c * HH + h]);
}

__global__ __launch_bounds__(256, 2)
void attn_kernel(const float* __restrict__ x,
                 const unsigned short* __restrict__ wT,
                 float* __restrict__ out) {
  __shared__ unsigned short wbuf[64 * WSTR];  // staged W^T; reused for P
  __shared__ unsigned short qs[64 * QSTR];    // q row-major [t][h]
  __shared__ unsigned short ks[64 * QSTR];    // k row-major [t][h]
  __shared__ unsigned short vts[64 * QSTR];   // v transposed [h][t]

  const int b    = blockIdx.x;
  const int tid  = threadIdx.x;
  const int wave = tid >> 6;
  const int lane = tid & 63;
  const int quad = lane >> 4;
  const int l15  = lane & 15;
  const int mbase = wave * 16;   // this wave's output-row tile

  // ---- x A-fragments in registers: A[m=l15][k=quad*8+j], k = ks_*32 + quad*8 + j
  // fp32 load (two float4 per chunk), convert to bf16 RNE.
  bf16x8 xfrag[4];
  {
    const float* xr = x + ((size_t)b * TT + mbase + l15) * CC + quad * 8;
    #pragma unroll
    for (int ks_ = 0; ks_ < 4; ++ks_) {
      f32x4 lo = *(const f32x4*)(xr + ks_ * 32);
      f32x4 hi = *(const f32x4*)(xr + ks_ * 32 + 4);
      bf16x8 f;
      #pragma unroll
      for (int j = 0; j < 4; ++j) {
        union { unsigned short u; __bf16 b; } cv;
        cv.u = f2bf(lo[j]); f[j] = cv.b;
        cv.u = f2bf(hi[j]); f[j + 4] = cv.b;
      }
      xfrag[ks_] = f;
    }
  }

  // ---- Phase 1: q, k, v projections (stream each W^T through wbuf)
  #pragma unroll
  for (int mat = 0; mat < 3; ++mat) {
    const unsigned short* wsrc = wT + mat * (CC * HH);
    #pragma unroll
    for (int r = 0; r < 4; ++r) {
      int flat = (r * 256 + tid) * 8;       // 0..8191
      int row  = flat >> 7;                 // / 128
      int col  = flat & 127;
      *(uint4*)(&wbuf[row * WSTR + col]) = *(const uint4*)(wsrc + flat);
    }
    __syncthreads();

    #pragma unroll
    for (int nt = 0; nt < 4; ++nt) {
      f32x4 acc = {0.f, 0.f, 0.f, 0.f};
      #pragma unroll
      for (int ks_ = 0; ks_ < 4; ++ks_) {
        // B[n=h][k=c]: row h = nt*16+l15 of W^T, c contiguous
        bf16x8 bfrag = *(const bf16x8*)(&wbuf[(nt * 16 + l15) * WSTR + ks_ * 32 + quad * 8]);
        acc = __builtin_amdgcn_mfma_f32_16x16x32_bf16(xfrag[ks_], bfrag, acc, 0, 0, 0);
      }
      // C/D layout: col = lane&15 (+16*nt), row = quad*4 + r (+mbase)
      #pragma unroll
      for (int r = 0; r < 4; ++r) {
        int row = mbase + quad * 4 + r;
        int col = nt * 16 + l15;
        unsigned short v = f2bf(acc[r]);
        if (mat == 0)      qs[row * QSTR + col] = v;
        else if (mat == 1) ks[row * QSTR + col] = v;
        else               vts[col * QSTR + row] = v;   // store v transposed
      }
    }
    __syncthreads();
  }

  // ---- Phase 2: S = q k^T * scale, causal mask, softmax -> P (bf16) into wbuf
  f32x4 sc[4];
  {
    bf16x8 aq[2];
    #pragma unroll
    for (int k2 = 0; k2 < 2; ++k2)
      aq[k2] = *(const bf16x8*)(&qs[(mbase + l15) * QSTR + k2 * 32 + quad * 8]);
    #pragma unroll
    for (int nt = 0; nt < 4; ++nt) {
      f32x4 acc = {0.f, 0.f, 0.f, 0.f};
      #pragma unroll
      for (int k2 = 0; k2 < 2; ++k2) {
        // B[n=s][k=h]: row s = nt*16+l15 of k, h contiguous
        bf16x8 bk = *(const bf16x8*)(&ks[(nt * 16 + l15) * QSTR + k2 * 32 + quad * 8]);
        acc = __builtin_amdgcn_mfma_f32_16x16x32_bf16(aq[k2], bk, acc, 0, 0, 0);
      }
      sc[nt] = acc;
    }
  }
  const float scale = 0.08838834764831845f;  // 128^-0.5 (embed dim, per reference!)
  #pragma unroll
  for (int r = 0; r < 4; ++r) {
    int row = mbase + quad * 4 + r;
    float vals[4];
    #pragma unroll
    for (int nt = 0; nt < 4; ++nt) {
      int col = nt * 16 + l15;
      float v = sc[nt][r] * scale;
      vals[nt] = (col <= row) ? v : -__builtin_inff();
    }
    // a row of S lives in this quad's 16 lanes x 4 regs -> 16-lane reduction
    float m = fmaxf(fmaxf(vals[0], vals[1]), fmaxf(vals[2], vals[3]));
    #pragma unroll
    for (int d = 1; d < 16; d <<= 1) m = fmaxf(m, __shfl_xor(m, d, 64));
    float s = 0.f;
    #pragma unroll
    for (int nt = 0; nt < 4; ++nt) { vals[nt] = __expf(vals[nt] - m); s += vals[nt]; }
    #pragma unroll
    for (int d = 1; d < 16; d <<= 1) s += __shfl_xor(s, d, 64);
    float inv = 1.f / s;
    #pragma unroll
    for (int nt = 0; nt < 4; ++nt)
      wbuf[row * WSTR + nt * 16 + l15] = f2bf(vals[nt] * inv);
  }
  __syncthreads();

  // ---- Phase 3: O = P @ V  (fp32 output!)
  bf16x8 ap[2];
  #pragma unroll
  for (int k2 = 0; k2 < 2; ++k2)
    ap[k2] = *(const bf16x8*)(&wbuf[(mbase + l15) * WSTR + k2 * 32 + quad * 8]);
  float* ob = out + ((size_t)b * TT) * HH;
  #pragma unroll
  for (int nt = 0; nt < 4; ++nt) {
    f32x4 acc = {0.f, 0.f, 0.f, 0.f};
    #pragma unroll
    for (int k2 = 0; k2 < 2; ++k2) {
      // B[n=h][k=s]: row h = nt*16+l15 of v^T, s contiguous
      bf16x8 bv = *(const bf16x8*)(&vts[(nt * 16 + l15) * QSTR + k2 * 32 + quad * 8]);
      acc = __builtin_amdgcn_mfma_f32_16x16x32_bf16(ap[k2], bv, acc, 0, 0, 0);
    }
    #pragma unroll
    for (int r = 0; r < 4; ++r) {
      int row = mbase + quad * 4 + r;
      ob[row * HH + nt * 16 + l15] = acc[r];   // fp32 store
    }
  }
}

extern "C" void kernel_launch(void* const* d_in, const int* in_sizes, int n_in,
                              void* d_out, int out_size, void* d_ws, size_t ws_size,
                              hipStream_t stream) {
  const float* x  = (const float*)d_in[0];
  const float* Wq = (const float*)d_in[1];
  const float* Wk = (const float*)d_in[2];
  const float* Wv = (const float*)d_in[3];
  unsigned short* wT = (unsigned short*)d_ws;   // 3*128*64*2 = 48 KiB scratch
  float* outp = (float*)d_out;

  transpose_w_kernel<<<(3 * CC * HH + 255) / 256, 256, 0, stream>>>(Wq, Wk, Wv, wT);
  attn_kernel<<<NB, 256, 0, stream>>>(x, wT, outp);
}